// Round 3
// baseline (526.735 us; speedup 1.0000x reference)
//
#include <hip/hip_runtime.h>

#define PP 2048     // P (pred rows)
#define SSEQ 2048   // S (key rows)
#define DDIM 1024   // D
#define NH 16       // heads
#define DH 64       // head dim

typedef __attribute__((ext_vector_type(4))) float f32x4;
typedef __attribute__((ext_vector_type(8))) short bf16x8;
typedef __attribute__((ext_vector_type(4))) short bf16x4;

__device__ __forceinline__ short f2bf(float f) {
  unsigned u = __builtin_bit_cast(unsigned, f);
  u += 0x7FFFu + ((u >> 16) & 1u);   // RNE
  return (short)(u >> 16);
}
__device__ __forceinline__ float bf2f(unsigned short u) {
  return __builtin_bit_cast(float, ((unsigned)u) << 16);
}

// ---------------- GEMM: Y[2048][1024] = X @ W^T + bias ----------------
// 64x128 tile, BK=32, 4 waves (2x2), wave = 32x64.
// XMODE: 0 = X fp32, 2 = X is sum of two bf16 buffers (ctx partials).
template<int XMODE, int YF32>
__device__ __forceinline__ void gemm_body(const void* __restrict__ Xv,
                                          const void* __restrict__ X2,
                                          const float* __restrict__ W,
                                          const float* __restrict__ bias,
                                          void* __restrict__ Yv) {
  __shared__ short As[64][40];
  __shared__ short Bs[128][40];
  const int tid = threadIdx.x, lane = tid & 63, wid = tid >> 6;
  const int wm = (wid >> 1) * 32, wn = (wid & 1) * 64;
  const int m0 = blockIdx.y * 64, n0 = blockIdx.x * 128;
  const int g = lane >> 4, ln = lane & 15;
  f32x4 acc[2][4] = {};
  for (int k0 = 0; k0 < DDIM; k0 += 32) {
    __syncthreads();
#pragma unroll
    for (int pass = 0; pass < 2; ++pass) {
      const int e = pass * 1024 + tid * 4;
      const int r = e >> 5, c = e & 31;
      if (XMODE == 0) {
        const float* X = (const float*)Xv;
        float4 x = *(const float4*)(X + (size_t)(m0 + r) * DDIM + k0 + c);
        bf16x4 xb; xb[0] = f2bf(x.x); xb[1] = f2bf(x.y); xb[2] = f2bf(x.z); xb[3] = f2bf(x.w);
        *(bf16x4*)&As[r][c] = xb;
      } else {
        const unsigned short* A0 = (const unsigned short*)Xv;
        const unsigned short* A1 = (const unsigned short*)X2;
        bf16x4 a0 = *(const bf16x4*)(A0 + (size_t)(m0 + r) * DDIM + k0 + c);
        bf16x4 a1 = *(const bf16x4*)(A1 + (size_t)(m0 + r) * DDIM + k0 + c);
        bf16x4 s;
#pragma unroll
        for (int u = 0; u < 4; ++u)
          s[u] = f2bf(bf2f((unsigned short)a0[u]) + bf2f((unsigned short)a1[u]));
        *(bf16x4*)&As[r][c] = s;
      }
    }
#pragma unroll
    for (int pass = 0; pass < 4; ++pass) {
      const int e = pass * 1024 + tid * 4;
      const int r = e >> 5, c = e & 31;
      float4 w = *(const float4*)(W + (size_t)(n0 + r) * DDIM + k0 + c);
      bf16x4 wb; wb[0] = f2bf(w.x); wb[1] = f2bf(w.y); wb[2] = f2bf(w.z); wb[3] = f2bf(w.w);
      *(bf16x4*)&Bs[r][c] = wb;
    }
    __syncthreads();
    bf16x8 a[2], b[4];
#pragma unroll
    for (int mi = 0; mi < 2; ++mi) a[mi] = *(const bf16x8*)&As[wm + mi * 16 + ln][g * 8];
#pragma unroll
    for (int ni = 0; ni < 4; ++ni) b[ni] = *(const bf16x8*)&Bs[wn + ni * 16 + ln][g * 8];
#pragma unroll
    for (int mi = 0; mi < 2; ++mi)
#pragma unroll
      for (int ni = 0; ni < 4; ++ni)
        acc[mi][ni] = __builtin_amdgcn_mfma_f32_16x16x32_bf16(a[mi], b[ni], acc[mi][ni], 0, 0, 0);
  }
#pragma unroll
  for (int mi = 0; mi < 2; ++mi)
#pragma unroll
    for (int ni = 0; ni < 4; ++ni)
#pragma unroll
      for (int r = 0; r < 4; ++r) {
        const int m = m0 + wm + mi * 16 + g * 4 + r;
        const int n = n0 + wn + ni * 16 + ln;
        const float v = acc[mi][ni][r] + bias[n];
        if (YF32) ((float*)Yv)[(size_t)m * DDIM + n] = v;
        else ((unsigned short*)Yv)[(size_t)m * DDIM + n] = (unsigned short)f2bf(v);
      }
}

__global__ __launch_bounds__(256, 4) void qkv_proj(
    const float* __restrict__ Q, const float* __restrict__ Kin, const float* __restrict__ V,
    const float* __restrict__ Wq, const float* __restrict__ Wk, const float* __restrict__ Wv,
    const float* __restrict__ bq, const float* __restrict__ bk, const float* __restrict__ bv,
    unsigned short* __restrict__ qb, unsigned short* __restrict__ kb, unsigned short* __restrict__ vb) {
  const int z = blockIdx.z;
  const float* X = (z == 0) ? Q : (z == 1) ? Kin : V;
  const float* W = (z == 0) ? Wq : (z == 1) ? Wk : Wv;
  const float* b = (z == 0) ? bq : (z == 1) ? bk : bv;
  unsigned short* Y = (z == 0) ? qb : (z == 1) ? kb : vb;
  gemm_body<0, 0>(X, nullptr, W, b, Y);
}

__global__ __launch_bounds__(256, 4) void out_proj(
    const unsigned short* __restrict__ ctxp0, const unsigned short* __restrict__ ctxp1,
    const float* __restrict__ Wo, const float* __restrict__ bo, float* __restrict__ out) {
  gemm_body<2, 1>(ctxp0, ctxp1, Wo, bo, out);
}

// ---------------- V transpose: vT[d][s] = vb[s][d] ----------------
__global__ __launch_bounds__(256) void transpose_v(
    const unsigned short* __restrict__ vb, unsigned short* __restrict__ vT) {
  __shared__ unsigned short t[64][72];
  const int tid = threadIdx.x;
  const int sb = blockIdx.x * 64, db = blockIdx.y * 64;
#pragma unroll
  for (int pass = 0; pass < 2; ++pass) {
    const int e = pass * 2048 + tid * 8;
    const int r = e >> 6, c = e & 63;
    *(bf16x8*)&t[r][c] = *(const bf16x8*)(vb + (size_t)(sb + r) * DDIM + db + c);
  }
  __syncthreads();
#pragma unroll
  for (int pass = 0; pass < 2; ++pass) {
    const int e = pass * 2048 + tid * 8;
    const int r = e >> 6, c = e & 63;   // r: d row, c: s col
    bf16x8 ov;
#pragma unroll
    for (int u = 0; u < 8; ++u) ov[u] = (short)t[c + u][r];
    *(bf16x8*)(vT + (size_t)(db + r) * SSEQ + sb + c) = ov;
  }
}

// ---------------- scores v3: BARRIER-FREE ----------------
// raw = (q@k^T*scale + prev)*gate; per-(wave,row) partial (m,l).
// grid: (P/64, 4, NH); block 256 = 4 waves. Each wave owns a private 32-col
// strip per 128-col tile; K-frags from global (L2-resident); per-wave LDS
// repack (same-wave lgkmcnt only, no __syncthreads anywhere).
__global__ __launch_bounds__(256, 3) void scores_kernel(
    const unsigned short* __restrict__ qb, const unsigned short* __restrict__ kb,
    const float* __restrict__ prev, const float* __restrict__ ch_gate,
    float* __restrict__ raw, float* __restrict__ m_part, float* __restrict__ l_part) {
  __shared__ float Rs[4][32][68];   // [wave][col-in-strip][row(+pad)]
  const int tid = threadIdx.x, lane = tid & 63, w = tid >> 6;
  const int pt = blockIdx.x, sg = blockIdx.y, h = blockIdx.z;
  const int p0 = pt * 64;
  const int g = lane >> 4, ln = lane & 15;
  const int b8 = lane & 7, c8 = lane >> 3;   // epilogue: col=b8*4+i, row=8it+c8

  // Q fragments: rows p0 + mi*16 + ln, k = ks*32 + g*8 .. +7
  bf16x8 aq[4][2];
#pragma unroll
  for (int mi = 0; mi < 4; ++mi)
#pragma unroll
    for (int ks = 0; ks < 2; ++ks)
      aq[mi][ks] = *(const bf16x8*)(qb + (size_t)(p0 + mi * 16 + ln) * DDIM + h * DH + ks * 32 + g * 8);

  const int pc = p0 >> 8;
  float mrun[8], lrun[8];
#pragma unroll
  for (int i = 0; i < 8; ++i) { mrun[i] = -1e30f; lrun[i] = 0.f; }

  for (int t = 0; t < 4; ++t) {
    const int s0 = sg * 512 + t * 128;
    const int sw = s0 + w * 32;   // this wave's strip
    const float gate = (ch_gate[pc * 8 + (s0 >> 8)] >= 0.f) ? 1.f : 0.f;
    // prev prefetch: 8 float4 (rows 8it+c8, cols b8*4..+3) — hides HBM latency
    float4 pv[8];
#pragma unroll
    for (int it = 0; it < 8; ++it)
      pv[it] = *(const float4*)(prev + ((size_t)(p0 + 8 * it + c8) * NH + h) * SSEQ + sw + b8 * 4);
    // K fragments for the strip (L2-resident)
    bf16x8 bk_[2][2];
#pragma unroll
    for (int nj = 0; nj < 2; ++nj)
#pragma unroll
      for (int ks = 0; ks < 2; ++ks)
        bk_[nj][ks] = *(const bf16x8*)(kb + (size_t)(sw + nj * 16 + ln) * DDIM + h * DH + ks * 32 + g * 8);
    f32x4 acc[4][2] = {};
#pragma unroll
    for (int ks = 0; ks < 2; ++ks)
#pragma unroll
      for (int mi = 0; mi < 4; ++mi)
#pragma unroll
        for (int nj = 0; nj < 2; ++nj)
          acc[mi][nj] = __builtin_amdgcn_mfma_f32_16x16x32_bf16(aq[mi][ks], bk_[nj][ks], acc[mi][nj], 0, 0, 0);
    // per-wave repack: [col][row], b128 writes (rows contiguous)
#pragma unroll
    for (int mi = 0; mi < 4; ++mi)
#pragma unroll
      for (int nj = 0; nj < 2; ++nj)
        *(f32x4*)&Rs[w][nj * 16 + ln][mi * 16 + g * 4] = acc[mi][nj];
    // epilogue (compiler inserts lgkmcnt for the same-wave LDS dependence)
#pragma unroll
    for (int it = 0; it < 8; ++it) {
      const int row = 8 * it + c8;
      const int p = p0 + row;
      const int sq = sw + b8 * 4;
      float4 v;
      v.x = fmaf(Rs[w][b8 * 4 + 0][row], 0.125f, pv[it].x) * gate;
      v.y = fmaf(Rs[w][b8 * 4 + 1][row], 0.125f, pv[it].y) * gate;
      v.z = fmaf(Rs[w][b8 * 4 + 2][row], 0.125f, pv[it].z) * gate;
      v.w = fmaf(Rs[w][b8 * 4 + 3][row], 0.125f, pv[it].w) * gate;
      *(float4*)(raw + ((size_t)p * NH + h) * SSEQ + sq) = v;
      if (sq <= p) {
        const float v0 = v.x;
        const float v1 = (sq + 1 <= p) ? v.y : -1e30f;
        const float v2 = (sq + 2 <= p) ? v.z : -1e30f;
        const float v3 = (sq + 3 <= p) ? v.w : -1e30f;
        const float qm = fmaxf(fmaxf(v0, v1), fmaxf(v2, v3));
        const float mn = fmaxf(mrun[it], qm);
        lrun[it] = lrun[it] * __expf(mrun[it] - mn)
                 + __expf(v0 - mn) + __expf(v1 - mn) + __expf(v2 - mn) + __expf(v3 - mn);
        mrun[it] = mn;
      }
    }
  }
  // merge across the 8 lanes (same c8) sharing each row; write per-wave partial
#pragma unroll
  for (int it = 0; it < 8; ++it) {
    float m = mrun[it], l = lrun[it];
#pragma unroll
    for (int mask = 1; mask < 8; mask <<= 1) {
      const float mo = __shfl_xor(m, mask);
      const float lo = __shfl_xor(l, mask);
      const float mn = fmaxf(m, mo);
      l = l * __expf(m - mn) + lo * __expf(mo - mn);
      m = mn;
    }
    if (b8 == 0) {
      const int p = p0 + 8 * it + c8;
      const size_t idx = ((size_t)(sg * 4 + w) * NH + h) * PP + p;
      m_part[idx] = m;
      l_part[idx] = l;
    }
  }
}

// ---------------- attnpv v3: ZERO LDS, ZERO BARRIERS ----------------
// attn = exp(raw-m)/l (causal) written coalesced; P packed to bf16 A-frags
// in-register; V-frags from L2-resident vT; partial ctx per S-split.
// grid: (P/64, 2, NH); block 256 = 4 waves, wave owns 16 p-rows.
__global__ __launch_bounds__(256, 4) void attnpv_kernel(
    const float* __restrict__ raw, const unsigned short* __restrict__ vT,
    const float* __restrict__ m_part, const float* __restrict__ l_part,
    float* __restrict__ attn, unsigned short* __restrict__ ctxp) {
  const int tid = threadIdx.x, lane = tid & 63, w = tid >> 6;
  const int pt = blockIdx.x, ss = blockIdx.y, h = blockIdx.z;
  const int p0 = pt * 64, wr = w * 16;
  const int g = lane >> 4, ln = lane & 15;
  const int myp = p0 + wr + ln;   // this lane's A-frag row

  // merge 16 per-wave partials for row myp
  float m = -1e30f, l = 0.f;
#pragma unroll
  for (int sgw = 0; sgw < 16; ++sgw) {
    const size_t idx = ((size_t)sgw * NH + h) * PP + myp;
    const float mo = m_part[idx];
    const float lo = l_part[idx];
    const float mn = fmaxf(m, mo);
    l = l * __expf(m - mn) + lo * __expf(mo - mn);
    m = mn;
  }
  const float mm = m;
  const float il = 1.f / l;

  unsigned short* ctx = ctxp + (size_t)ss * PP * DDIM;
  f32x4 acc[4] = {};
  for (int st = 0; st < 8; ++st) {
    const int s0 = ss * 1024 + st * 128;
    if (s0 > p0 + 63) {   // fully masked: zero-fill wave's 16 rows x 128 cols
      const float4 z = {0.f, 0.f, 0.f, 0.f};
#pragma unroll
      for (int i = 0; i < 8; ++i) {
        const int e = i * 1024 + lane * 16;       // byte offset in 16x512B
        const int row = e >> 9, colf = (e & 511) >> 2;
        *(float4*)(attn + ((size_t)(p0 + wr + row) * NH + h) * SSEQ + s0 + colf) = z;
      }
      continue;
    }
    const size_t rbase = ((size_t)myp * NH + h) * SSEQ + s0;
    bf16x8 pa[4];
#pragma unroll
    for (int ks = 0; ks < 4; ++ks) {
      const int c0 = ks * 32 + g * 8;
      const float4 r0 = *(const float4*)(raw + rbase + c0);
      const float4 r1 = *(const float4*)(raw + rbase + c0 + 4);
      const int sb = s0 + c0;
      float4 a0, a1;
      a0.x = (sb + 0 <= myp) ? __expf(r0.x - mm) * il : 0.f;
      a0.y = (sb + 1 <= myp) ? __expf(r0.y - mm) * il : 0.f;
      a0.z = (sb + 2 <= myp) ? __expf(r0.z - mm) * il : 0.f;
      a0.w = (sb + 3 <= myp) ? __expf(r0.w - mm) * il : 0.f;
      a1.x = (sb + 4 <= myp) ? __expf(r1.x - mm) * il : 0.f;
      a1.y = (sb + 5 <= myp) ? __expf(r1.y - mm) * il : 0.f;
      a1.z = (sb + 6 <= myp) ? __expf(r1.z - mm) * il : 0.f;
      a1.w = (sb + 7 <= myp) ? __expf(r1.w - mm) * il : 0.f;
      *(float4*)(attn + rbase + c0) = a0;
      *(float4*)(attn + rbase + c0 + 4) = a1;
      bf16x8 pk;
      pk[0] = f2bf(a0.x); pk[1] = f2bf(a0.y); pk[2] = f2bf(a0.z); pk[3] = f2bf(a0.w);
      pk[4] = f2bf(a1.x); pk[5] = f2bf(a1.y); pk[6] = f2bf(a1.z); pk[7] = f2bf(a1.w);
      pa[ks] = pk;
    }
#pragma unroll
    for (int nj = 0; nj < 4; ++nj) {
#pragma unroll
      for (int ks = 0; ks < 4; ++ks) {
        const bf16x8 bv = *(const bf16x8*)(vT + (size_t)(h * DH + nj * 16 + ln) * SSEQ + s0 + ks * 32 + g * 8);
        acc[nj] = __builtin_amdgcn_mfma_f32_16x16x32_bf16(pa[ks], bv, acc[nj], 0, 0, 0);
      }
    }
  }
#pragma unroll
  for (int nj = 0; nj < 4; ++nj)
#pragma unroll
    for (int r = 0; r < 4; ++r) {
      const int p = p0 + wr + g * 4 + r;
      ctx[(size_t)p * DDIM + h * DH + nj * 16 + ln] = (unsigned short)f2bf(acc[nj][r]);
    }
}

extern "C" void kernel_launch(void* const* d_in, const int* in_sizes, int n_in,
                              void* d_out, int out_size, void* d_ws, size_t ws_size,
                              hipStream_t stream) {
  (void)in_sizes; (void)n_in; (void)out_size; (void)ws_size;
  const float* Q    = (const float*)d_in[0];
  const float* K    = (const float*)d_in[1];
  const float* V    = (const float*)d_in[2];
  const float* prev = (const float*)d_in[3];
  const float* Wq   = (const float*)d_in[4];
  const float* bq   = (const float*)d_in[5];
  const float* Wk   = (const float*)d_in[6];
  const float* bk   = (const float*)d_in[7];
  const float* Wv   = (const float*)d_in[8];
  const float* bv   = (const float*)d_in[9];
  const float* Wo   = (const float*)d_in[10];
  const float* bo   = (const float*)d_in[11];
  const float* ch_gate = (const float*)d_in[12];
  // d_in[13] = attn_mask — recomputed analytically.

  float* out  = (float*)d_out;                       // (2048,1024)
  float* attn = out + (size_t)PP * DDIM;             // (2048,16,2048)
  float* raw  = attn + (size_t)PP * NH * SSEQ;       // (2048,16,2048)

  unsigned short* qb    = (unsigned short*)d_ws;            // 4MB each
  unsigned short* kb    = qb + (size_t)PP * DDIM;
  unsigned short* vb    = kb + (size_t)PP * DDIM;
  unsigned short* vT    = vb + (size_t)PP * DDIM;
  unsigned short* ctxp  = vT + (size_t)DDIM * SSEQ;         // 2 x 4MB bf16
  float* m_part = (float*)(ctxp + (size_t)2 * PP * DDIM);   // (16,16,2048) f32
  float* l_part = m_part + (size_t)16 * NH * PP;

  dim3 blk(256);
  qkv_proj<<<dim3(DDIM / 128, PP / 64, 3), blk, 0, stream>>>(
      Q, K, V, Wq, Wk, Wv, bq, bk, bv, qb, kb, vb);
  transpose_v<<<dim3(SSEQ / 64, DDIM / 64), blk, 0, stream>>>(vb, vT);
  scores_kernel<<<dim3(PP / 64, 4, NH), blk, 0, stream>>>(
      qb, kb, prev, ch_gate, raw, m_part, l_part);
  attnpv_kernel<<<dim3(PP / 64, 2, NH), blk, 0, stream>>>(
      raw, vT, m_part, l_part, attn, ctxp);
  out_proj<<<dim3(DDIM / 128, PP / 64), blk, 0, stream>>>(
      ctxp, ctxp + (size_t)PP * DDIM, Wo, bo, out);
}